// Round 1
// baseline (844.356 us; speedup 1.0000x reference)
//
#include <hip/hip_runtime.h>
#include <math.h>

// Problem constants
#define N_NODES 8192
#define KNBR    32
#define D_LOCAL 256
#define PDIM    128
#define BINS    64
#define N_RBF   16
#define REL_CLIP 32
#define REL_DIM  66   // 2*REL_CLIP + 2
#define N_ATOMS  5

__device__ __forceinline__ float gelu_tanh(float x) {
    float x3 = x * x * x;
    float z = 0.7978845608028654f * (x + 0.044715f * x3);
    float zc = fminf(fmaxf(z, -15.f), 15.f);
    float e2 = __expf(2.f * zc);
    float t = (e2 - 1.f) / (e2 + 1.f);
    return 0.5f * x * (1.f + t);
}

// ---------------- Kernel A: per-node frames + local projections ----------------
// grid = N/8 blocks, 128 threads. Each block handles 8 nodes.
__global__ __launch_bounds__(128) void node_kernel(
    const float* __restrict__ local, const float* __restrict__ pos,
    const float* __restrict__ W_loc_i, const float* __restrict__ W_loc_j,
    float* __restrict__ R_ws, float* __restrict__ loci_ws, float* __restrict__ locj_ws)
{
    __shared__ float lloc[8][D_LOCAL];
    const int tid = threadIdx.x;
    const int base = blockIdx.x * 8;

    // stage 8 local rows as float4
    {
        const float4* src = reinterpret_cast<const float4*>(local + (size_t)base * D_LOCAL);
        float4* dst = reinterpret_cast<float4*>(&lloc[0][0]);
        #pragma unroll
        for (int it = 0; it < 4; ++it) dst[tid + it * 128] = src[tid + it * 128];
    }

    // frames: threads 0..7, one node each
    if (tid < 8) {
        const int n = base + tid;
        const float* pp = pos + (size_t)n * 15;
        float nx = pp[0], ny = pp[1], nz = pp[2];
        float cax = pp[3], cay = pp[4], caz = pp[5];
        float cx = pp[6], cy = pp[7], cz = pp[8];
        float e1x = cx - cax, e1y = cy - cay, e1z = cz - caz;
        float n1 = sqrtf(e1x*e1x + e1y*e1y + e1z*e1z) + 1e-8f;
        e1x /= n1; e1y /= n1; e1z /= n1;
        float v2x = nx - cax, v2y = ny - cay, v2z = nz - caz;
        float dp = v2x*e1x + v2y*e1y + v2z*e1z;
        float wx = v2x - dp*e1x, wy = v2y - dp*e1y, wz = v2z - dp*e1z;
        float n2 = sqrtf(wx*wx + wy*wy + wz*wz) + 1e-8f;
        float e2x = wx/n2, e2y = wy/n2, e2z = wz/n2;
        float e3x = e1y*e2z - e1z*e2y;
        float e3y = e1z*e2x - e1x*e2z;
        float e3z = e1x*e2y - e1y*e2x;
        float* R = R_ws + (size_t)n * 9;   // R[b*3+a] = e_b[a]
        R[0] = e1x; R[1] = e1y; R[2] = e1z;
        R[3] = e2x; R[4] = e2y; R[5] = e2z;
        R[6] = e3x; R[7] = e3y; R[8] = e3z;
    }
    __syncthreads();

    // projections: thread t computes channel t for all 8 nodes
    float ai[8], aj[8];
    #pragma unroll
    for (int s = 0; s < 8; ++s) { ai[s] = 0.f; aj[s] = 0.f; }
    for (int c4 = 0; c4 < D_LOCAL / 4; ++c4) {
        float wi0 = W_loc_i[(c4*4+0)*PDIM + tid];
        float wi1 = W_loc_i[(c4*4+1)*PDIM + tid];
        float wi2 = W_loc_i[(c4*4+2)*PDIM + tid];
        float wi3 = W_loc_i[(c4*4+3)*PDIM + tid];
        float wj0 = W_loc_j[(c4*4+0)*PDIM + tid];
        float wj1 = W_loc_j[(c4*4+1)*PDIM + tid];
        float wj2 = W_loc_j[(c4*4+2)*PDIM + tid];
        float wj3 = W_loc_j[(c4*4+3)*PDIM + tid];
        #pragma unroll
        for (int s = 0; s < 8; ++s) {
            float4 lv = *reinterpret_cast<const float4*>(&lloc[s][c4*4]);
            ai[s] += lv.x*wi0 + lv.y*wi1 + lv.z*wi2 + lv.w*wi3;
            aj[s] += lv.x*wj0 + lv.y*wj1 + lv.z*wj2 + lv.w*wj3;
        }
    }
    #pragma unroll
    for (int s = 0; s < 8; ++s) {
        loci_ws[(size_t)(base + s) * PDIM + tid] = ai[s];
        locj_ws[(size_t)(base + s) * PDIM + tid] = aj[s];
    }
}

// ---------------- Kernel B: per-node pair features + LN + MLP + log_softmax ----------------
// grid = N blocks, 256 threads. Block handles node i's 32 neighbors.
#define NFEAT 43
__global__ __launch_bounds__(256, 2) void pair_kernel(
    const float* __restrict__ pos, const int* __restrict__ neighbours,
    const int* __restrict__ resi, const int* __restrict__ chain,
    const int* __restrict__ batch, const int* __restrict__ mask,
    const float* __restrict__ W_relpos, const float* __restrict__ W_dist,
    const float* __restrict__ W_dir, const float* __restrict__ W_rot,
    const float* __restrict__ W_pvec,
    const float* __restrict__ ln_scale, const float* __restrict__ ln_bias,
    const float* __restrict__ W1, const float* __restrict__ b1,
    const float* __restrict__ W2, const float* __restrict__ b2,
    const float* __restrict__ R_ws, const float* __restrict__ loci_ws,
    const float* __restrict__ locj_ws, float* __restrict__ out)
{
    __shared__ float WfA[NFEAT * PDIM];          // 22016 B
    __shared__ float fpair[KNBR][PDIM];          // 16384 B
    __shared__ float feat[KNBR][44];             // 5632 B
    __shared__ float hidden[KNBR][2 * PDIM];     // 32768 B
    __shared__ float lociS[PDIM];
    __shared__ float lnsc[PDIM], lnb[PDIM];
    __shared__ float RiS[12], caiS[4];
    __shared__ float muS[KNBR], rstdS[KNBR];
    __shared__ int   jidxS[KNBR], codeS[KNBR];
    __shared__ float pmaskS[KNBR];

    const int tid = threadIdx.x;
    const int i = blockIdx.x;

    // --- stage weights + per-i data ---
    for (int e = tid; e < 16 * PDIM; e += 256) WfA[e] = W_dist[e];
    for (int e = tid; e < 3 * PDIM;  e += 256) WfA[16 * PDIM + e] = W_dir[e];
    for (int e = tid; e < 9 * PDIM;  e += 256) WfA[19 * PDIM + e] = W_rot[e];
    for (int e = tid; e < 15 * PDIM; e += 256) WfA[28 * PDIM + e] = W_pvec[e];
    if (tid < PDIM) {
        lociS[tid] = loci_ws[(size_t)i * PDIM + tid];
        lnsc[tid] = ln_scale[tid];
        lnb[tid] = ln_bias[tid];
    }
    if (tid < 9) RiS[tid] = R_ws[(size_t)i * 9 + tid];
    if (tid < 3) caiS[tid] = pos[(size_t)i * 15 + 3 + tid];
    __syncthreads();

    // --- features: one thread per neighbor ---
    if (tid < KNBR) {
        const int k = tid;
        const int nb = neighbours[(size_t)i * KNBR + k];
        const int j = nb < 0 ? 0 : nb;
        jidxS[k] = j;
        const int mi = mask[i], mj = mask[j];
        pmaskS[k] = (mi != 0 && mj != 0 && nb != -1) ? 1.f : 0.f;
        int rel = resi[j] - resi[i];
        rel = rel < -REL_CLIP ? -REL_CLIP : (rel > REL_CLIP ? REL_CLIP : rel);
        rel += REL_CLIP;
        bool same = (chain[j] == chain[i]) && (batch[j] == batch[i]);
        codeS[k] = same ? rel : (REL_DIM - 1);

        const float cax = caiS[0], cay = caiS[1], caz = caiS[2];
        const float* pj = pos + (size_t)j * 15;
        float dx = pj[3] - cax, dy = pj[4] - cay, dz = pj[5] - caz;
        float d = sqrtf(dx*dx + dy*dy + dz*dz);
        float inv = 1.f / (d + 1e-8f);
        float ux = dx * inv, uy = dy * inv, uz = dz * inv;
        // f_dist
        #pragma unroll
        for (int r = 0; r < N_RBF; ++r) {
            float cr = (22.f / 15.f) * r;
            float dd = d - cr;
            feat[k][r] = __expf(-dd * dd * (1.f / 3.78125f));
        }
        float Ri[9];
        #pragma unroll
        for (int q = 0; q < 9; ++q) Ri[q] = RiS[q];
        // f_dir
        #pragma unroll
        for (int b = 0; b < 3; ++b)
            feat[k][16 + b] = Ri[b*3+0]*ux + Ri[b*3+1]*uy + Ri[b*3+2]*uz;
        // f_rot
        float Rj[9];
        #pragma unroll
        for (int q = 0; q < 9; ++q) Rj[q] = R_ws[(size_t)j * 9 + q];
        #pragma unroll
        for (int b = 0; b < 3; ++b)
            #pragma unroll
            for (int c = 0; c < 3; ++c)
                feat[k][19 + b*3 + c] = Ri[b*3+0]*Rj[c*3+0] + Ri[b*3+1]*Rj[c*3+1] + Ri[b*3+2]*Rj[c*3+2];
        // f_pv
        #pragma unroll
        for (int m = 0; m < N_ATOMS; ++m) {
            float px = pj[m*3+0] - cax, py = pj[m*3+1] - cay, pz = pj[m*3+2] - caz;
            #pragma unroll
            for (int b = 0; b < 3; ++b)
                feat[k][28 + m*3 + b] = Ri[b*3+0]*px + Ri[b*3+1]*py + Ri[b*3+2]*pz;
        }
    }
    __syncthreads();

    // --- pair accumulation: 2 k-rows per pass, 128 channels each ---
    {
        const int t = tid & 127;
        const int half = tid >> 7;
        for (int rep = 0; rep < 16; ++rep) {
            const int k = rep * 2 + half;
            float acc = W_relpos[(size_t)codeS[k] * PDIM + t]
                      + lociS[t]
                      + locj_ws[(size_t)jidxS[k] * PDIM + t];
            #pragma unroll
            for (int c = 0; c < NFEAT; ++c)
                acc += feat[k][c] * WfA[c * PDIM + t];
            fpair[k][t] = acc * pmaskS[k];
        }
    }
    __syncthreads();

    // --- LayerNorm stats: 8 threads per k-row ---
    {
        const int g = tid & 7;
        const int k = tid >> 3;
        float s = 0.f, sq = 0.f;
        #pragma unroll
        for (int jj = 0; jj < 16; ++jj) {
            float v = fpair[k][g + jj * 8];
            s += v; sq += v * v;
        }
        #pragma unroll
        for (int m = 1; m < 8; m <<= 1) {
            s  += __shfl_xor(s, m, 64);
            sq += __shfl_xor(sq, m, 64);
        }
        if (g == 0) {
            float mu = s * (1.f / PDIM);
            float var = sq * (1.f / PDIM) - mu * mu;
            muS[k] = mu;
            rstdS[k] = rsqrtf(var + 1e-5f);
        }
    }
    __syncthreads();
    // normalize in place
    for (int e = tid; e < KNBR * PDIM; e += 256) {
        int k = e >> 7, c = e & 127;
        float v = (fpair[k][c] - muS[k]) * rstdS[k];
        fpair[k][c] = v * lnsc[c] + lnb[c];
    }
    __syncthreads();

    // --- MLP1: thread t computes hidden[:, t] for all 32 rows ---
    {
        float acc1[KNBR];
        const float b1v = b1[tid];
        #pragma unroll
        for (int kk = 0; kk < KNBR; ++kk) acc1[kk] = b1v;
        for (int c4 = 0; c4 < PDIM / 4; ++c4) {
            float w0 = W1[(size_t)(c4*4+0) * 256 + tid];
            float w1 = W1[(size_t)(c4*4+1) * 256 + tid];
            float w2 = W1[(size_t)(c4*4+2) * 256 + tid];
            float w3 = W1[(size_t)(c4*4+3) * 256 + tid];
            #pragma unroll
            for (int kk = 0; kk < KNBR; ++kk) {
                float4 p = *reinterpret_cast<const float4*>(&fpair[kk][c4*4]);
                acc1[kk] += p.x*w0 + p.y*w1 + p.z*w2 + p.w*w3;
            }
        }
        #pragma unroll
        for (int kk = 0; kk < KNBR; ++kk)
            hidden[kk][tid] = gelu_tanh(acc1[kk]);
    }
    __syncthreads();

    // --- MLP2 + log_softmax: wave w handles k-rows [w*8, w*8+8), lane = bin ---
    {
        const int wid = tid >> 6;
        const int lane = tid & 63;
        const int k0 = wid * 8;
        float acc2[8];
        #pragma unroll
        for (int kk = 0; kk < 8; ++kk) acc2[kk] = 0.f;
        for (int h4 = 0; h4 < 64; ++h4) {
            float w0 = W2[(size_t)(h4*4+0) * BINS + lane];
            float w1 = W2[(size_t)(h4*4+1) * BINS + lane];
            float w2v = W2[(size_t)(h4*4+2) * BINS + lane];
            float w3 = W2[(size_t)(h4*4+3) * BINS + lane];
            #pragma unroll
            for (int kk = 0; kk < 8; ++kk) {
                float4 hv = *reinterpret_cast<const float4*>(&hidden[k0 + kk][h4*4]);
                acc2[kk] += hv.x*w0 + hv.y*w1 + hv.z*w2v + hv.w*w3;
            }
        }
        const float b2v = b2[lane];
        #pragma unroll
        for (int kk = 0; kk < 8; ++kk) {
            float v = acc2[kk] + b2v;
            float m = v;
            #pragma unroll
            for (int s = 1; s < 64; s <<= 1) m = fmaxf(m, __shfl_xor(m, s, 64));
            float e = __expf(v - m);
            float ssum = e;
            #pragma unroll
            for (int s = 1; s < 64; s <<= 1) ssum += __shfl_xor(ssum, s, 64);
            float outv = v - m - __logf(ssum);
            out[(((size_t)i * KNBR + (k0 + kk)) << 6) + lane] = outv;
        }
    }
}

extern "C" void kernel_launch(void* const* d_in, const int* in_sizes, int n_in,
                              void* d_out, int out_size, void* d_ws, size_t ws_size,
                              hipStream_t stream) {
    (void)in_sizes; (void)n_in; (void)out_size; (void)ws_size;
    const float* local   = (const float*)d_in[0];
    const float* pos     = (const float*)d_in[1];
    const int* neighbours= (const int*)d_in[2];
    const int* resi      = (const int*)d_in[3];
    const int* chain     = (const int*)d_in[4];
    const int* batch     = (const int*)d_in[5];
    const int* mask      = (const int*)d_in[6];
    const float* W_relpos= (const float*)d_in[7];
    const float* W_dist  = (const float*)d_in[8];
    const float* W_dir   = (const float*)d_in[9];
    const float* W_rot   = (const float*)d_in[10];
    const float* W_pvec  = (const float*)d_in[11];
    const float* W_loc_i = (const float*)d_in[12];
    const float* W_loc_j = (const float*)d_in[13];
    const float* ln_scale= (const float*)d_in[14];
    const float* ln_bias = (const float*)d_in[15];
    const float* W1      = (const float*)d_in[16];
    const float* b1      = (const float*)d_in[17];
    const float* W2      = (const float*)d_in[18];
    const float* b2      = (const float*)d_in[19];
    float* out = (float*)d_out;

    // workspace layout
    float* R_ws    = (float*)d_ws;                            // N*9 floats
    float* loci_ws = R_ws + (size_t)N_NODES * 9;              // N*128
    float* locj_ws = loci_ws + (size_t)N_NODES * PDIM;        // N*128

    hipLaunchKernelGGL(node_kernel, dim3(N_NODES / 8), dim3(128), 0, stream,
                       local, pos, W_loc_i, W_loc_j, R_ws, loci_ws, locj_ws);
    hipLaunchKernelGGL(pair_kernel, dim3(N_NODES), dim3(256), 0, stream,
                       pos, neighbours, resi, chain, batch, mask,
                       W_relpos, W_dist, W_dir, W_rot, W_pvec,
                       ln_scale, ln_bias, W1, b1, W2, b2,
                       R_ws, loci_ws, locj_ws, out);
}

// Round 2
// 254.251 us; speedup vs baseline: 3.3210x; 3.3210x over previous
//
#include <hip/hip_runtime.h>
#include <math.h>

// Problem constants
#define N_NODES 8192
#define KNBR    32
#define D_LOCAL 256
#define PDIM    128
#define BINS    64
#define N_RBF   16
#define REL_CLIP 32
#define REL_DIM  66
#define N_ATOMS  5

typedef unsigned short ushort_t;
typedef short v8s __attribute__((ext_vector_type(8)));
typedef float v4f __attribute__((ext_vector_type(4)));

__device__ __forceinline__ float gelu_tanh(float x) {
    float x3 = x * x * x;
    float z = 0.7978845608028654f * (x + 0.044715f * x3);
    float zc = fminf(fmaxf(z, -15.f), 15.f);
    float e2 = __expf(2.f * zc);
    float t = (e2 - 1.f) / (e2 + 1.f);
    return 0.5f * x * (1.f + t);
}

__device__ __forceinline__ ushort_t f2bf(float f) {
    unsigned int u = __float_as_uint(f);
    u += 0x7fffu + ((u >> 16) & 1u);
    return (ushort_t)(u >> 16);
}

// ---------------- Prep: bf16 transposed weights ----------------
// WfT [128 cols][64 k] (k 0..15 dist, 16..18 dir, 19..27 rot, 28..42 pvec, 43..63 zero)
// W1T [256 cols][128 k], W2T [64 cols][256 k]
__global__ __launch_bounds__(256) void prep_kernel(
    const float* __restrict__ W_dist, const float* __restrict__ W_dir,
    const float* __restrict__ W_rot, const float* __restrict__ W_pvec,
    const float* __restrict__ W1, const float* __restrict__ W2,
    ushort_t* __restrict__ WfT, ushort_t* __restrict__ W1T, ushort_t* __restrict__ W2T)
{
    int idx = blockIdx.x * 256 + threadIdx.x;
    if (idx < 8192) {
        int col = idx >> 6, k = idx & 63;
        float v = 0.f;
        if (k < 16)      v = W_dist[k * PDIM + col];
        else if (k < 19) v = W_dir[(k - 16) * PDIM + col];
        else if (k < 28) v = W_rot[(k - 19) * PDIM + col];
        else if (k < 43) v = W_pvec[(k - 28) * PDIM + col];
        WfT[idx] = f2bf(v);
    } else if (idx < 8192 + 32768) {
        int o = idx - 8192;
        int col = o >> 7, k = o & 127;
        W1T[o] = f2bf(W1[(size_t)k * 256 + col]);
    } else if (idx < 8192 + 32768 + 16384) {
        int o = idx - 8192 - 32768;
        int col = o >> 8, k = o & 255;
        W2T[o] = f2bf(W2[(size_t)k * BINS + col]);
    }
}

// ---------------- Kernel A: per-node frames + local projections ----------------
__global__ __launch_bounds__(128) void node_kernel(
    const float* __restrict__ local, const float* __restrict__ pos,
    const float* __restrict__ W_loc_i, const float* __restrict__ W_loc_j,
    float* __restrict__ R_ws, float* __restrict__ loci_ws, float* __restrict__ locj_ws)
{
    __shared__ float lloc[8][D_LOCAL];
    const int tid = threadIdx.x;
    const int base = blockIdx.x * 8;

    {
        const float4* src = reinterpret_cast<const float4*>(local + (size_t)base * D_LOCAL);
        float4* dst = reinterpret_cast<float4*>(&lloc[0][0]);
        #pragma unroll
        for (int it = 0; it < 4; ++it) dst[tid + it * 128] = src[tid + it * 128];
    }

    if (tid < 8) {
        const int n = base + tid;
        const float* pp = pos + (size_t)n * 15;
        float nx = pp[0], ny = pp[1], nz = pp[2];
        float cax = pp[3], cay = pp[4], caz = pp[5];
        float cx = pp[6], cy = pp[7], cz = pp[8];
        float e1x = cx - cax, e1y = cy - cay, e1z = cz - caz;
        float n1 = sqrtf(e1x*e1x + e1y*e1y + e1z*e1z) + 1e-8f;
        e1x /= n1; e1y /= n1; e1z /= n1;
        float v2x = nx - cax, v2y = ny - cay, v2z = nz - caz;
        float dp = v2x*e1x + v2y*e1y + v2z*e1z;
        float wx = v2x - dp*e1x, wy = v2y - dp*e1y, wz = v2z - dp*e1z;
        float n2 = sqrtf(wx*wx + wy*wy + wz*wz) + 1e-8f;
        float e2x = wx/n2, e2y = wy/n2, e2z = wz/n2;
        float e3x = e1y*e2z - e1z*e2y;
        float e3y = e1z*e2x - e1x*e2z;
        float e3z = e1x*e2y - e1y*e2x;
        float* R = R_ws + (size_t)n * 9;
        R[0] = e1x; R[1] = e1y; R[2] = e1z;
        R[3] = e2x; R[4] = e2y; R[5] = e2z;
        R[6] = e3x; R[7] = e3y; R[8] = e3z;
    }
    __syncthreads();

    float ai[8], aj[8];
    #pragma unroll
    for (int s = 0; s < 8; ++s) { ai[s] = 0.f; aj[s] = 0.f; }
    for (int c4 = 0; c4 < D_LOCAL / 4; ++c4) {
        float wi0 = W_loc_i[(c4*4+0)*PDIM + tid];
        float wi1 = W_loc_i[(c4*4+1)*PDIM + tid];
        float wi2 = W_loc_i[(c4*4+2)*PDIM + tid];
        float wi3 = W_loc_i[(c4*4+3)*PDIM + tid];
        float wj0 = W_loc_j[(c4*4+0)*PDIM + tid];
        float wj1 = W_loc_j[(c4*4+1)*PDIM + tid];
        float wj2 = W_loc_j[(c4*4+2)*PDIM + tid];
        float wj3 = W_loc_j[(c4*4+3)*PDIM + tid];
        #pragma unroll
        for (int s = 0; s < 8; ++s) {
            float4 lv = *reinterpret_cast<const float4*>(&lloc[s][c4*4]);
            ai[s] += lv.x*wi0 + lv.y*wi1 + lv.z*wi2 + lv.w*wi3;
            aj[s] += lv.x*wj0 + lv.y*wj1 + lv.z*wj2 + lv.w*wj3;
        }
    }
    #pragma unroll
    for (int s = 0; s < 8; ++s) {
        loci_ws[(size_t)(base + s) * PDIM + tid] = ai[s];
        locj_ws[(size_t)(base + s) * PDIM + tid] = aj[s];
    }
}

// ---------------- Kernel B: MFMA pair pipeline ----------------
__global__ __launch_bounds__(256, 3) void pair_kernel(
    const float* __restrict__ pos, const int* __restrict__ neighbours,
    const int* __restrict__ resi, const int* __restrict__ chain,
    const int* __restrict__ batch, const int* __restrict__ mask,
    const float* __restrict__ W_relpos,
    const float* __restrict__ ln_scale, const float* __restrict__ ln_bias,
    const float* __restrict__ b1, const float* __restrict__ b2,
    const float* __restrict__ R_ws, const float* __restrict__ loci_ws,
    const float* __restrict__ locj_ws,
    const ushort_t* __restrict__ WfT, const ushort_t* __restrict__ W1T,
    const ushort_t* __restrict__ W2T, float* __restrict__ out)
{
    __shared__ __align__(16) ushort_t featB[KNBR][72];     // 4608 B, cols 43..63 zero
    __shared__ __align__(16) char bufA[KNBR * 264 * 2];    // 16896 B: fpair f32 [32][132] then hiddenB bf16 [32][264]
    __shared__ __align__(16) ushort_t pairB[KNBR][136];    // 8704 B
    __shared__ float logitsS[KNBR][BINS];                  // 8192 B
    __shared__ float lociS[PDIM], lnscS[PDIM], lnbS[PDIM];
    __shared__ float RiS[9], caiS[3];
    __shared__ float muS[KNBR], rstdS[KNBR];
    __shared__ int   jidxS[KNBR], codeS[KNBR];
    __shared__ float pmaskS[KNBR];

    float* fpairS = (float*)bufA;         // [32][132]
    ushort_t* hiddenB = (ushort_t*)bufA;  // [32][264]

    const int tid = threadIdx.x;
    const int i = blockIdx.x;
    const int wid = tid >> 6;
    const int lane = tid & 63;
    const int r15 = lane & 15;
    const int b8 = (lane >> 4) * 8;       // k sub-block for A/B frags
    const int r4 = (lane >> 4) * 4;       // row sub-block for C frags

    // --- P0: stage per-i small data ---
    if (tid < PDIM) {
        lociS[tid] = loci_ws[(size_t)i * PDIM + tid];
        lnscS[tid] = ln_scale[tid];
        lnbS[tid] = ln_bias[tid];
    }
    if (tid < 9) RiS[tid] = R_ws[(size_t)i * 9 + tid];
    if (tid < 3) caiS[tid] = pos[(size_t)i * 15 + 3 + tid];
    __syncthreads();

    // --- P0b: features (one thread per neighbor) -> featB bf16 ---
    if (tid < KNBR) {
        const int k = tid;
        const int nb = neighbours[(size_t)i * KNBR + k];
        const int j = nb < 0 ? 0 : nb;
        jidxS[k] = j;
        const int mi = mask[i], mj = mask[j];
        pmaskS[k] = (mi != 0 && mj != 0 && nb != -1) ? 1.f : 0.f;
        int rel = resi[j] - resi[i];
        rel = rel < -REL_CLIP ? -REL_CLIP : (rel > REL_CLIP ? REL_CLIP : rel);
        rel += REL_CLIP;
        bool same = (chain[j] == chain[i]) && (batch[j] == batch[i]);
        codeS[k] = same ? rel : (REL_DIM - 1);

        float f[43];
        const float cax = caiS[0], cay = caiS[1], caz = caiS[2];
        const float* pj = pos + (size_t)j * 15;
        float dx = pj[3] - cax, dy = pj[4] - cay, dz = pj[5] - caz;
        float d = sqrtf(dx*dx + dy*dy + dz*dz);
        float inv = 1.f / (d + 1e-8f);
        float ux = dx * inv, uy = dy * inv, uz = dz * inv;
        #pragma unroll
        for (int r = 0; r < N_RBF; ++r) {
            float cr = (22.f / 15.f) * r;
            float dd = d - cr;
            f[r] = __expf(-dd * dd * (1.f / 3.78125f));
        }
        float Ri[9];
        #pragma unroll
        for (int q = 0; q < 9; ++q) Ri[q] = RiS[q];
        #pragma unroll
        for (int b = 0; b < 3; ++b)
            f[16 + b] = Ri[b*3+0]*ux + Ri[b*3+1]*uy + Ri[b*3+2]*uz;
        float Rj[9];
        #pragma unroll
        for (int q = 0; q < 9; ++q) Rj[q] = R_ws[(size_t)j * 9 + q];
        #pragma unroll
        for (int b = 0; b < 3; ++b)
            #pragma unroll
            for (int c = 0; c < 3; ++c)
                f[19 + b*3 + c] = Ri[b*3+0]*Rj[c*3+0] + Ri[b*3+1]*Rj[c*3+1] + Ri[b*3+2]*Rj[c*3+2];
        #pragma unroll
        for (int m = 0; m < N_ATOMS; ++m) {
            float px = pj[m*3+0] - cax, py = pj[m*3+1] - cay, pz = pj[m*3+2] - caz;
            #pragma unroll
            for (int b = 0; b < 3; ++b)
                f[28 + m*3 + b] = Ri[b*3+0]*px + Ri[b*3+1]*py + Ri[b*3+2]*pz;
        }
        #pragma unroll
        for (int c = 0; c < 43; ++c) featB[k][c] = f2bf(f[c]);
        #pragma unroll
        for (int c = 43; c < 64; ++c) featB[k][c] = 0;
    }
    __syncthreads();

    // --- P1: pair GEMM (32x128 = feat[32x64] @ WfT^T[64x128]) + adds ---
    {
        const int rt = wid & 1;
        const int ctb = (wid >> 1) * 4;
        v4f pacc[4];
        #pragma unroll
        for (int c = 0; c < 4; ++c) { pacc[c][0]=0.f; pacc[c][1]=0.f; pacc[c][2]=0.f; pacc[c][3]=0.f; }
        const int arow = rt * 16 + r15;
        #pragma unroll
        for (int ks = 0; ks < 2; ++ks) {
            v8s aF = *(const v8s*)&featB[arow][ks*32 + b8];
            #pragma unroll
            for (int c = 0; c < 4; ++c) {
                v8s bF = *(const v8s*)(WfT + ((ctb+c)*16 + r15)*64 + ks*32 + b8);
                pacc[c] = __builtin_amdgcn_mfma_f32_16x16x32_bf16(aF, bF, pacc[c], 0, 0, 0);
            }
        }
        const int row0 = rt * 16 + r4;
        #pragma unroll
        for (int c = 0; c < 4; ++c) {
            const int col = (ctb+c)*16 + r15;
            const float lv = lociS[col];
            #pragma unroll
            for (int r = 0; r < 4; ++r) {
                const int row = row0 + r;
                float v = pacc[c][r]
                        + W_relpos[(size_t)codeS[row] * PDIM + col]
                        + lv
                        + locj_ws[(size_t)jidxS[row] * PDIM + col];
                fpairS[row * 132 + col] = v * pmaskS[row];
            }
        }
    }
    __syncthreads();

    // --- P2: LN stats (8 threads per row) ---
    {
        const int g = tid & 7;
        const int k = tid >> 3;
        float s = 0.f, sq = 0.f;
        #pragma unroll
        for (int jj = 0; jj < 16; ++jj) {
            float v = fpairS[k * 132 + g + jj * 8];
            s += v; sq += v * v;
        }
        #pragma unroll
        for (int m = 1; m < 8; m <<= 1) {
            s  += __shfl_xor(s, m, 64);
            sq += __shfl_xor(sq, m, 64);
        }
        if (g == 0) {
            float mu = s * (1.f / PDIM);
            float var = sq * (1.f / PDIM) - mu * mu;
            muS[k] = mu;
            rstdS[k] = rsqrtf(var + 1e-5f);
        }
    }
    __syncthreads();

    // --- P3: normalize -> pairB bf16 ---
    for (int e = tid; e < KNBR * PDIM; e += 256) {
        int k = e >> 7, c = e & 127;
        float v = (fpairS[k * 132 + c] - muS[k]) * rstdS[k] * lnscS[c] + lnbS[c];
        pairB[k][c] = f2bf(v);
    }
    __syncthreads();

    // --- P4: MLP1 MFMA (32x256 = pair[32x128] @ W1T^T) + gelu -> hiddenB ---
    {
        v4f acc1[2][4];
        #pragma unroll
        for (int rt = 0; rt < 2; ++rt)
            #pragma unroll
            for (int ct = 0; ct < 4; ++ct) { acc1[rt][ct][0]=0.f; acc1[rt][ct][1]=0.f; acc1[rt][ct][2]=0.f; acc1[rt][ct][3]=0.f; }
        #pragma unroll
        for (int ks = 0; ks < 4; ++ks) {
            v8s aF0 = *(const v8s*)&pairB[r15][ks*32 + b8];
            v8s aF1 = *(const v8s*)&pairB[16 + r15][ks*32 + b8];
            #pragma unroll
            for (int ct = 0; ct < 4; ++ct) {
                v8s bF = *(const v8s*)(W1T + (size_t)(wid*64 + ct*16 + r15)*128 + ks*32 + b8);
                acc1[0][ct] = __builtin_amdgcn_mfma_f32_16x16x32_bf16(aF0, bF, acc1[0][ct], 0, 0, 0);
                acc1[1][ct] = __builtin_amdgcn_mfma_f32_16x16x32_bf16(aF1, bF, acc1[1][ct], 0, 0, 0);
            }
        }
        #pragma unroll
        for (int ct = 0; ct < 4; ++ct) {
            const int col = wid*64 + ct*16 + r15;
            const float b1v = b1[col];
            #pragma unroll
            for (int rt = 0; rt < 2; ++rt) {
                #pragma unroll
                for (int r = 0; r < 4; ++r) {
                    const int row = rt*16 + r4 + r;
                    hiddenB[row * 264 + col] = f2bf(gelu_tanh(acc1[rt][ct][r] + b1v));
                }
            }
        }
    }
    __syncthreads();

    // --- P5: MLP2 MFMA (32x64 = hidden[32x256] @ W2T^T) + b2 -> logits ---
    {
        const int rt2 = wid >> 1;
        const int ct0 = (wid & 1) * 2;
        v4f acc2[2];
        #pragma unroll
        for (int c = 0; c < 2; ++c) { acc2[c][0]=0.f; acc2[c][1]=0.f; acc2[c][2]=0.f; acc2[c][3]=0.f; }
        #pragma unroll
        for (int ks = 0; ks < 8; ++ks) {
            v8s aF = *(const v8s*)&hiddenB[(rt2*16 + r15) * 264 + ks*32 + b8];
            #pragma unroll
            for (int c = 0; c < 2; ++c) {
                v8s bF = *(const v8s*)(W2T + (size_t)((ct0+c)*16 + r15)*256 + ks*32 + b8);
                acc2[c] = __builtin_amdgcn_mfma_f32_16x16x32_bf16(aF, bF, acc2[c], 0, 0, 0);
            }
        }
        #pragma unroll
        for (int c = 0; c < 2; ++c) {
            const int col = (ct0+c)*16 + r15;
            const float b2v = b2[col];
            #pragma unroll
            for (int r = 0; r < 4; ++r) {
                const int row = rt2*16 + r4 + r;
                logitsS[row][col] = acc2[c][r] + b2v;
            }
        }
    }
    __syncthreads();

    // --- P6: log_softmax (wave per 8 rows, lane = bin) ---
    {
        const int k0 = wid * 8;
        #pragma unroll
        for (int kk = 0; kk < 8; ++kk) {
            float v = logitsS[k0 + kk][lane];
            float m = v;
            #pragma unroll
            for (int s = 1; s < 64; s <<= 1) m = fmaxf(m, __shfl_xor(m, s, 64));
            float e = __expf(v - m);
            float ssum = e;
            #pragma unroll
            for (int s = 1; s < 64; s <<= 1) ssum += __shfl_xor(ssum, s, 64);
            float outv = v - m - __logf(ssum);
            out[(((size_t)i * KNBR + (k0 + kk)) << 6) + lane] = outv;
        }
    }
}

extern "C" void kernel_launch(void* const* d_in, const int* in_sizes, int n_in,
                              void* d_out, int out_size, void* d_ws, size_t ws_size,
                              hipStream_t stream) {
    (void)in_sizes; (void)n_in; (void)out_size; (void)ws_size;
    const float* local   = (const float*)d_in[0];
    const float* pos     = (const float*)d_in[1];
    const int* neighbours= (const int*)d_in[2];
    const int* resi      = (const int*)d_in[3];
    const int* chain     = (const int*)d_in[4];
    const int* batch     = (const int*)d_in[5];
    const int* mask      = (const int*)d_in[6];
    const float* W_relpos= (const float*)d_in[7];
    const float* W_dist  = (const float*)d_in[8];
    const float* W_dir   = (const float*)d_in[9];
    const float* W_rot   = (const float*)d_in[10];
    const float* W_pvec  = (const float*)d_in[11];
    const float* W_loc_i = (const float*)d_in[12];
    const float* W_loc_j = (const float*)d_in[13];
    const float* ln_scale= (const float*)d_in[14];
    const float* ln_bias = (const float*)d_in[15];
    const float* W1      = (const float*)d_in[16];
    const float* b1      = (const float*)d_in[17];
    const float* W2      = (const float*)d_in[18];
    const float* b2      = (const float*)d_in[19];
    float* out = (float*)d_out;

    // workspace layout
    float* R_ws    = (float*)d_ws;                         // 8192*9 f32
    float* loci_ws = R_ws + (size_t)N_NODES * 9;           // 8192*128 f32
    float* locj_ws = loci_ws + (size_t)N_NODES * PDIM;     // 8192*128 f32
    ushort_t* WfT  = (ushort_t*)(locj_ws + (size_t)N_NODES * PDIM); // 128*64 bf16
    ushort_t* W1T  = WfT + 128 * 64;                       // 256*128 bf16
    ushort_t* W2T  = W1T + 256 * 128;                      // 64*256 bf16

    hipLaunchKernelGGL(prep_kernel, dim3(224), dim3(256), 0, stream,
                       W_dist, W_dir, W_rot, W_pvec, W1, W2, WfT, W1T, W2T);
    hipLaunchKernelGGL(node_kernel, dim3(N_NODES / 8), dim3(128), 0, stream,
                       local, pos, W_loc_i, W_loc_j, R_ws, loci_ws, locj_ws);
    hipLaunchKernelGGL(pair_kernel, dim3(N_NODES), dim3(256), 0, stream,
                       pos, neighbours, resi, chain, batch, mask, W_relpos,
                       ln_scale, ln_bias, b1, b2,
                       R_ws, loci_ws, locj_ws, WfT, W1T, W2T, out);
}

// Round 3
// 181.722 us; speedup vs baseline: 4.6464x; 1.3991x over previous
//
#include <hip/hip_runtime.h>
#include <math.h>

#define N_NODES 8192
#define KNBR    32
#define D_LOCAL 256
#define PDIM    128
#define BINS    64
#define N_RBF   16
#define REL_CLIP 32
#define REL_DIM  66
#define N_ATOMS  5
#define NPB     2
#define ROWS    64          // NPB*KNBR
#define KF      128         // pair GEMM K: 43 feat + 66 one-hot + 19 zero

typedef unsigned short ushort_t;
typedef short v8s __attribute__((ext_vector_type(8)));
typedef float v4f __attribute__((ext_vector_type(4)));

__device__ __forceinline__ ushort_t f2bf(float f) {
    unsigned int u = __float_as_uint(f);
    u += 0x7fffu + ((u >> 16) & 1u);
    return (ushort_t)(u >> 16);
}
// gelu_tanh(x) == x * sigmoid(2*0.7978845608*(x + 0.044715 x^3))  (exact identity)
__device__ __forceinline__ float fast_gelu(float x) {
    float x2 = x * x;
    float y = x * fmaf(x2, 0.07135481627f, 1.5957691216f); // y = 2*z
    float e = __expf(-y);
    return x / (1.f + e);   // x -> -inf: e -> inf, x/inf -> -0  (correct limit)
}

// swizzled LDS addressing (XOR chunk swizzle, T2 pattern)
__device__ __forceinline__ int fAddr(int row, int col) {        // bf16 [64][128]
    return row * KF + ((((col >> 3) ^ (row & 7)) << 3) | (col & 7));
}
__device__ __forceinline__ int hAddr(int row, int col) {        // bf16 [64][256]
    return row * 256 + ((((col >> 3) ^ (row & 7)) << 3) | (col & 7));
}
__device__ __forceinline__ int pAddr(int row, int col) {        // f32 [64][132]
    return row * 132 + ((((col >> 2) ^ (row & 7)) << 2) | (col & 3));
}
__device__ __forceinline__ int gAddr(int row, int col) {        // f32 [64][64]
    return row * 64 + ((((col >> 2) ^ (row & 7)) << 2) | (col & 3));
}

// ---------------- Prep: bf16 transposed/combined weights ----------------
// Wcomb [128 cols][128 k]: k 0..15 dist, 16..18 dir, 19..27 rot, 28..42 pvec,
//                          43..108 relpos one-hot block, 109..127 zero
// W1T [256 cols][128 k], W2T [64 cols][256 k]
__global__ __launch_bounds__(256) void prep_kernel(
    const float* __restrict__ W_dist, const float* __restrict__ W_dir,
    const float* __restrict__ W_rot, const float* __restrict__ W_pvec,
    const float* __restrict__ W_relpos,
    const float* __restrict__ W1, const float* __restrict__ W2,
    ushort_t* __restrict__ Wcomb, ushort_t* __restrict__ W1T, ushort_t* __restrict__ W2T)
{
    int idx = blockIdx.x * 256 + threadIdx.x;
    if (idx < 16384) {
        int col = idx >> 7, k = idx & 127;
        float v = 0.f;
        if (k < 16)       v = W_dist[k * PDIM + col];
        else if (k < 19)  v = W_dir[(k - 16) * PDIM + col];
        else if (k < 28)  v = W_rot[(k - 19) * PDIM + col];
        else if (k < 43)  v = W_pvec[(k - 28) * PDIM + col];
        else if (k < 109) v = W_relpos[(size_t)(k - 43) * PDIM + col];
        Wcomb[idx] = f2bf(v);
    } else if (idx < 16384 + 32768) {
        int o = idx - 16384;
        int col = o >> 7, k = o & 127;
        W1T[o] = f2bf(W1[(size_t)k * 256 + col]);
    } else if (idx < 16384 + 32768 + 16384) {
        int o = idx - 49152;
        int col = o >> 8, k = o & 255;
        W2T[o] = f2bf(W2[(size_t)k * BINS + col]);
    }
}

// ---------------- Kernel A: per-node frames + local projections ----------------
__global__ __launch_bounds__(128) void node_kernel(
    const float* __restrict__ local, const float* __restrict__ pos,
    const float* __restrict__ W_loc_i, const float* __restrict__ W_loc_j,
    float* __restrict__ R_ws, float* __restrict__ loci_ws, float* __restrict__ locj_ws)
{
    __shared__ float lloc[8][D_LOCAL];
    const int tid = threadIdx.x;
    const int base = blockIdx.x * 8;

    {
        const float4* src = reinterpret_cast<const float4*>(local + (size_t)base * D_LOCAL);
        float4* dst = reinterpret_cast<float4*>(&lloc[0][0]);
        #pragma unroll
        for (int it = 0; it < 4; ++it) dst[tid + it * 128] = src[tid + it * 128];
    }

    if (tid < 8) {
        const int n = base + tid;
        const float* pp = pos + (size_t)n * 15;
        float nx = pp[0], ny = pp[1], nz = pp[2];
        float cax = pp[3], cay = pp[4], caz = pp[5];
        float cx = pp[6], cy = pp[7], cz = pp[8];
        float e1x = cx - cax, e1y = cy - cay, e1z = cz - caz;
        float n1 = sqrtf(e1x*e1x + e1y*e1y + e1z*e1z) + 1e-8f;
        e1x /= n1; e1y /= n1; e1z /= n1;
        float v2x = nx - cax, v2y = ny - cay, v2z = nz - caz;
        float dp = v2x*e1x + v2y*e1y + v2z*e1z;
        float wx = v2x - dp*e1x, wy = v2y - dp*e1y, wz = v2z - dp*e1z;
        float n2 = sqrtf(wx*wx + wy*wy + wz*wz) + 1e-8f;
        float e2x = wx/n2, e2y = wy/n2, e2z = wz/n2;
        float e3x = e1y*e2z - e1z*e2y;
        float e3y = e1z*e2x - e1x*e2z;
        float e3z = e1x*e2y - e1y*e2x;
        float* R = R_ws + (size_t)n * 9;
        R[0] = e1x; R[1] = e1y; R[2] = e1z;
        R[3] = e2x; R[4] = e2y; R[5] = e2z;
        R[6] = e3x; R[7] = e3y; R[8] = e3z;
    }
    __syncthreads();

    float ai[8], aj[8];
    #pragma unroll
    for (int s = 0; s < 8; ++s) { ai[s] = 0.f; aj[s] = 0.f; }
    for (int c4 = 0; c4 < D_LOCAL / 4; ++c4) {
        float wi0 = W_loc_i[(c4*4+0)*PDIM + tid];
        float wi1 = W_loc_i[(c4*4+1)*PDIM + tid];
        float wi2 = W_loc_i[(c4*4+2)*PDIM + tid];
        float wi3 = W_loc_i[(c4*4+3)*PDIM + tid];
        float wj0 = W_loc_j[(c4*4+0)*PDIM + tid];
        float wj1 = W_loc_j[(c4*4+1)*PDIM + tid];
        float wj2 = W_loc_j[(c4*4+2)*PDIM + tid];
        float wj3 = W_loc_j[(c4*4+3)*PDIM + tid];
        #pragma unroll
        for (int s = 0; s < 8; ++s) {
            float4 lv = *reinterpret_cast<const float4*>(&lloc[s][c4*4]);
            ai[s] += lv.x*wi0 + lv.y*wi1 + lv.z*wi2 + lv.w*wi3;
            aj[s] += lv.x*wj0 + lv.y*wj1 + lv.z*wj2 + lv.w*wj3;
        }
    }
    #pragma unroll
    for (int s = 0; s < 8; ++s) {
        loci_ws[(size_t)(base + s) * PDIM + tid] = ai[s];
        locj_ws[(size_t)(base + s) * PDIM + tid] = aj[s];
    }
}

// ---------------- Kernel B: 2-node MFMA pair pipeline ----------------
__global__ __launch_bounds__(256, 3) void pair_kernel(
    const float* __restrict__ pos, const int* __restrict__ neighbours,
    const int* __restrict__ resi, const int* __restrict__ chain,
    const int* __restrict__ batch, const int* __restrict__ mask,
    const float* __restrict__ ln_scale, const float* __restrict__ ln_bias,
    const float* __restrict__ b1, const float* __restrict__ b2,
    const float* __restrict__ R_ws, const float* __restrict__ loci_ws,
    const float* __restrict__ locj_ws,
    const ushort_t* __restrict__ Wcomb, const ushort_t* __restrict__ W1T,
    const ushort_t* __restrict__ W2T, float* __restrict__ out)
{
    __shared__ __align__(16) ushort_t SH0[ROWS * KF];   // 16384 B: featB / pairB / logits(f32)
    __shared__ __align__(16) float    SH1[ROWS * 132];  // 33792 B: fpair f32 / hiddenB bf16
    __shared__ float lnscS[PDIM], lnbS[PDIM];
    __shared__ float RiS[NPB][9], caiS[NPB][3];
    __shared__ int   jidxS[ROWS], codeS[ROWS];
    __shared__ float pmaskS[ROWS];

    ushort_t* featB   = SH0;
    ushort_t* pairB   = SH0;              // alias (featB dead after P1)
    float*    logitsS = (float*)SH0;      // alias (pairB dead after P4)
    float*    fpairS  = SH1;
    ushort_t* hiddenB = (ushort_t*)SH1;   // alias (fpair dead after P2/3)

    const int tid = threadIdx.x;
    const int ib = blockIdx.x;
    const int base = ib * NPB;
    const int wid = tid >> 6;
    const int lane = tid & 63;
    const int c15 = lane & 15;
    const int hi = lane >> 4;
    const int b8 = hi * 8;
    const int r4 = hi * 4;

    // ---------- P0a: meta + stage + zero one-hot region ----------
    if (tid < PDIM) { lnscS[tid] = ln_scale[tid]; lnbS[tid] = ln_bias[tid]; }
    else if (tid < PDIM + NPB * 9) {
        int q = tid - PDIM;
        RiS[q / 9][q % 9] = R_ws[(size_t)(base + q / 9) * 9 + (q % 9)];
    } else if (tid < PDIM + NPB * 9 + NPB * 3) {
        int q = tid - PDIM - NPB * 9;
        caiS[q / 3][q % 3] = pos[(size_t)(base + q / 3) * 15 + 3 + (q % 3)];
    }
    if (tid < ROWS) {
        const int row = tid;
        const int node = base + (row >> 5);
        const int nb = neighbours[(size_t)node * KNBR + (row & 31)];
        const int j = nb < 0 ? 0 : nb;
        jidxS[row] = j;
        pmaskS[row] = (mask[node] != 0 && mask[j] != 0 && nb != -1) ? 1.f : 0.f;
        int rel = resi[j] - resi[node];
        rel = rel < -REL_CLIP ? -REL_CLIP : (rel > REL_CLIP ? REL_CLIP : rel);
        rel += REL_CLIP;
        bool same = (chain[j] == chain[node]) && (batch[j] == batch[node]);
        codeS[row] = same ? rel : (REL_DIM - 1);
    }
    {   // zero logical chunks 6..15 (cols 48..127)
        const v8s z = {0,0,0,0,0,0,0,0};
        for (int e = tid; e < ROWS * 10; e += 256) {
            int row = e / 10, ch = 6 + (e % 10);
            *(v8s*)&featB[row * KF + ((ch ^ (row & 7)) << 3)] = z;
        }
    }
    __syncthreads();

    // ---------- P0b: role-split features + locj/loci prefetch ----------
    if (wid == 0) {
        // role A: RBF (cols 0..15) + dir (16..18)
        const int row = lane;
        const int node = row >> 5;
        const int j = jidxS[row];
        const float* pj = pos + (size_t)j * 15;
        const float cax = caiS[node][0], cay = caiS[node][1], caz = caiS[node][2];
        float dx = pj[3]-cax, dy = pj[4]-cay, dz = pj[5]-caz;
        float d = sqrtf(dx*dx + dy*dy + dz*dz);
        float inv = 1.f / (d + 1e-8f);
        float ux = dx*inv, uy = dy*inv, uz = dz*inv;
        #pragma unroll
        for (int r = 0; r < N_RBF; ++r) {
            float dd = d - (22.f / 15.f) * r;
            featB[fAddr(row, r)] = f2bf(__expf(-dd * dd * (1.f / 3.78125f)));
        }
        #pragma unroll
        for (int b = 0; b < 3; ++b)
            featB[fAddr(row, 16 + b)] =
                f2bf(RiS[node][b*3]*ux + RiS[node][b*3+1]*uy + RiS[node][b*3+2]*uz);
    } else if (wid == 1) {
        // role B: rot (19..27) + pv (28..42) + zeros 43..47 + one-hot
        const int row = lane;
        const int node = row >> 5;
        const int j = jidxS[row];
        const float* pj = pos + (size_t)j * 15;
        float Ri[9], Rj[9];
        #pragma unroll
        for (int q = 0; q < 9; ++q) Ri[q] = RiS[node][q];
        #pragma unroll
        for (int q = 0; q < 9; ++q) Rj[q] = R_ws[(size_t)j * 9 + q];
        #pragma unroll
        for (int b = 0; b < 3; ++b)
            #pragma unroll
            for (int c = 0; c < 3; ++c)
                featB[fAddr(row, 19 + b*3 + c)] =
                    f2bf(Ri[b*3]*Rj[c*3] + Ri[b*3+1]*Rj[c*3+1] + Ri[b*3+2]*Rj[c*3+2]);
        const float cax = caiS[node][0], cay = caiS[node][1], caz = caiS[node][2];
        #pragma unroll
        for (int m = 0; m < N_ATOMS; ++m) {
            float px = pj[m*3]-cax, py = pj[m*3+1]-cay, pz = pj[m*3+2]-caz;
            #pragma unroll
            for (int b = 0; b < 3; ++b)
                featB[fAddr(row, 28 + m*3 + b)] =
                    f2bf(Ri[b*3]*px + Ri[b*3+1]*py + Ri[b*3+2]*pz);
        }
        #pragma unroll
        for (int c = 43; c < 48; ++c) featB[fAddr(row, c)] = 0;
        featB[fAddr(row, 43 + codeS[row])] = (ushort_t)0x3F80;  // bf16 1.0
    } else {
        // waves 2,3: fpairInit = locj[j[row]] + loci[node]
        const int t = tid - 128;
        for (int e = t; e < ROWS * 32; e += 128) {
            int row = e >> 5, cg = e & 31;
            float4 lj = *(const float4*)&locj_ws[(size_t)jidxS[row] * PDIM + cg * 4];
            float4 li = *(const float4*)&loci_ws[(size_t)(base + (row >> 5)) * PDIM + cg * 4];
            float4 v;
            v.x = lj.x + li.x; v.y = lj.y + li.y; v.z = lj.z + li.z; v.w = lj.w + li.w;
            *(float4*)&fpairS[pAddr(row, cg * 4)] = v;
        }
    }
    __syncthreads();

    // ---------- P1: pair GEMM [64x128] = featB[64x128] @ Wcomb^T + init, *mask ----------
    {
        v4f acc[4][2];
        #pragma unroll
        for (int rt = 0; rt < 4; ++rt)
            #pragma unroll
            for (int ct = 0; ct < 2; ++ct) { acc[rt][ct][0]=0.f; acc[rt][ct][1]=0.f; acc[rt][ct][2]=0.f; acc[rt][ct][3]=0.f; }
        const int colbase = wid * 32;
        #pragma unroll
        for (int ks = 0; ks < 4; ++ks) {
            v8s aF[4];
            #pragma unroll
            for (int rt = 0; rt < 4; ++rt)
                aF[rt] = *(const v8s*)&featB[fAddr(rt*16 + c15, ks*32 + b8)];
            #pragma unroll
            for (int ct = 0; ct < 2; ++ct) {
                v8s bF = *(const v8s*)&Wcomb[(size_t)(colbase + ct*16 + c15) * KF + ks*32 + b8];
                #pragma unroll
                for (int rt = 0; rt < 4; ++rt)
                    acc[rt][ct] = __builtin_amdgcn_mfma_f32_16x16x32_bf16(aF[rt], bF, acc[rt][ct], 0, 0, 0);
            }
        }
        #pragma unroll
        for (int rt = 0; rt < 4; ++rt)
            #pragma unroll
            for (int ct = 0; ct < 2; ++ct) {
                const int col = colbase + ct*16 + c15;
                #pragma unroll
                for (int r = 0; r < 4; ++r) {
                    const int row = rt*16 + r4 + r;
                    const int a = pAddr(row, col);
                    fpairS[a] = (acc[rt][ct][r] + fpairS[a]) * pmaskS[row];
                }
            }
    }
    __syncthreads();

    // ---------- P2+P3 fused: LN stats + normalize -> pairB bf16 ----------
    {
        const int row = tid >> 2;
        const int grp = tid & 3;
        v4f f[8];
        #pragma unroll
        for (int t = 0; t < 8; ++t)
            f[t] = *(const v4f*)&fpairS[row * 132 + (((grp*8 + t) ^ (row & 7)) << 2)];
        float s = 0.f, sq = 0.f;
        #pragma unroll
        for (int t = 0; t < 8; ++t)
            #pragma unroll
            for (int q = 0; q < 4; ++q) { float v = f[t][q]; s += v; sq += v * v; }
        s  += __shfl_xor(s, 1, 64);  sq += __shfl_xor(sq, 1, 64);
        s  += __shfl_xor(s, 2, 64);  sq += __shfl_xor(sq, 2, 64);
        const float mu = s * (1.f / PDIM);
        const float rstd = rsqrtf(sq * (1.f / PDIM) - mu * mu + 1e-5f);
        const float nm = -mu * rstd;
        #pragma unroll
        for (int t = 0; t < 8; ++t) {
            const int col = grp * 32 + t * 4;
            ushort4 u;
            float v0 = fmaf(fmaf(f[t][0], rstd, nm), lnscS[col+0], lnbS[col+0]);
            float v1 = fmaf(fmaf(f[t][1], rstd, nm), lnscS[col+1], lnbS[col+1]);
            float v2 = fmaf(fmaf(f[t][2], rstd, nm), lnscS[col+2], lnbS[col+2]);
            float v3 = fmaf(fmaf(f[t][3], rstd, nm), lnscS[col+3], lnbS[col+3]);
            u.x = f2bf(v0); u.y = f2bf(v1); u.z = f2bf(v2); u.w = f2bf(v3);
            *(ushort4*)&pairB[fAddr(row, col)] = u;
        }
    }
    __syncthreads();

    // ---------- P4: MLP1 [64x256] = pairB @ W1T^T, gelu -> hiddenB ----------
    {
        v4f acc[4][4];
        #pragma unroll
        for (int rt = 0; rt < 4; ++rt)
            #pragma unroll
            for (int ct = 0; ct < 4; ++ct) { acc[rt][ct][0]=0.f; acc[rt][ct][1]=0.f; acc[rt][ct][2]=0.f; acc[rt][ct][3]=0.f; }
        const int colbase = wid * 64;
        #pragma unroll
        for (int ks = 0; ks < 4; ++ks) {
            v8s aF[4];
            #pragma unroll
            for (int rt = 0; rt < 4; ++rt)
                aF[rt] = *(const v8s*)&pairB[fAddr(rt*16 + c15, ks*32 + b8)];
            #pragma unroll
            for (int ct = 0; ct < 4; ++ct) {
                v8s bF = *(const v8s*)&W1T[(size_t)(colbase + ct*16 + c15) * PDIM + ks*32 + b8];
                #pragma unroll
                for (int rt = 0; rt < 4; ++rt)
                    acc[rt][ct] = __builtin_amdgcn_mfma_f32_16x16x32_bf16(aF[rt], bF, acc[rt][ct], 0, 0, 0);
            }
        }
        #pragma unroll
        for (int ct = 0; ct < 4; ++ct) {
            const int col = colbase + ct*16 + c15;
            const float b1v = b1[col];
            #pragma unroll
            for (int rt = 0; rt < 4; ++rt)
                #pragma unroll
                for (int r = 0; r < 4; ++r) {
                    const int row = rt*16 + r4 + r;
                    hiddenB[hAddr(row, col)] = f2bf(fast_gelu(acc[rt][ct][r] + b1v));
                }
        }
    }
    __syncthreads();

    // ---------- P5: MLP2 [64x64] = hiddenB @ W2T^T + b2 -> logits ----------
    {
        v4f acc[4];
        #pragma unroll
        for (int rt = 0; rt < 4; ++rt) { acc[rt][0]=0.f; acc[rt][1]=0.f; acc[rt][2]=0.f; acc[rt][3]=0.f; }
        const int col = wid * 16 + c15;
        #pragma unroll
        for (int ks = 0; ks < 8; ++ks) {
            v8s bF = *(const v8s*)&W2T[(size_t)col * 256 + ks*32 + b8];
            #pragma unroll
            for (int rt = 0; rt < 4; ++rt) {
                v8s aF = *(const v8s*)&hiddenB[hAddr(rt*16 + c15, ks*32 + b8)];
                acc[rt] = __builtin_amdgcn_mfma_f32_16x16x32_bf16(aF, bF, acc[rt], 0, 0, 0);
            }
        }
        const float b2v = b2[col];
        #pragma unroll
        for (int rt = 0; rt < 4; ++rt)
            #pragma unroll
            for (int r = 0; r < 4; ++r)
                logitsS[gAddr(rt*16 + r4 + r, col)] = acc[rt][r] + b2v;
    }
    __syncthreads();

    // ---------- P6: log_softmax, 4 threads/row, direct global store ----------
    {
        const int row = tid >> 2;
        const int grp = tid & 3;
        float v[16];
        #pragma unroll
        for (int t = 0; t < 4; ++t) {
            v4f x = *(const v4f*)&logitsS[row * 64 + (((grp*4 + t) ^ (row & 7)) << 2)];
            v[t*4+0] = x[0]; v[t*4+1] = x[1]; v[t*4+2] = x[2]; v[t*4+3] = x[3];
        }
        float M = v[0];
        #pragma unroll
        for (int q = 1; q < 16; ++q) M = fmaxf(M, v[q]);
        M = fmaxf(M, __shfl_xor(M, 1, 64));
        M = fmaxf(M, __shfl_xor(M, 2, 64));
        float S = 0.f;
        #pragma unroll
        for (int q = 0; q < 16; ++q) S += __expf(v[q] - M);
        S += __shfl_xor(S, 1, 64);
        S += __shfl_xor(S, 2, 64);
        const float lz = M + __logf(S);
        const size_t obase = ((size_t)(ib * ROWS + row)) * BINS + grp * 16;
        #pragma unroll
        for (int t = 0; t < 4; ++t) {
            float4 o;
            o.x = v[t*4+0] - lz; o.y = v[t*4+1] - lz;
            o.z = v[t*4+2] - lz; o.w = v[t*4+3] - lz;
            *(float4*)&out[obase + t*4] = o;
        }
    }
}

extern "C" void kernel_launch(void* const* d_in, const int* in_sizes, int n_in,
                              void* d_out, int out_size, void* d_ws, size_t ws_size,
                              hipStream_t stream) {
    (void)in_sizes; (void)n_in; (void)out_size; (void)ws_size;
    const float* local   = (const float*)d_in[0];
    const float* pos     = (const float*)d_in[1];
    const int* neighbours= (const int*)d_in[2];
    const int* resi      = (const int*)d_in[3];
    const int* chain     = (const int*)d_in[4];
    const int* batch     = (const int*)d_in[5];
    const int* mask      = (const int*)d_in[6];
    const float* W_relpos= (const float*)d_in[7];
    const float* W_dist  = (const float*)d_in[8];
    const float* W_dir   = (const float*)d_in[9];
    const float* W_rot   = (const float*)d_in[10];
    const float* W_pvec  = (const float*)d_in[11];
    const float* W_loc_i = (const float*)d_in[12];
    const float* W_loc_j = (const float*)d_in[13];
    const float* ln_scale= (const float*)d_in[14];
    const float* ln_bias = (const float*)d_in[15];
    const float* W1      = (const float*)d_in[16];
    const float* b1      = (const float*)d_in[17];
    const float* W2      = (const float*)d_in[18];
    const float* b2      = (const float*)d_in[19];
    float* out = (float*)d_out;

    // workspace layout
    float* R_ws    = (float*)d_ws;                          // 8192*9 f32
    float* loci_ws = R_ws + (size_t)N_NODES * 9;            // 8192*128 f32
    float* locj_ws = loci_ws + (size_t)N_NODES * PDIM;      // 8192*128 f32
    ushort_t* Wcomb = (ushort_t*)(locj_ws + (size_t)N_NODES * PDIM); // 128*128 bf16
    ushort_t* W1T  = Wcomb + 128 * 128;                     // 256*128 bf16
    ushort_t* W2T  = W1T + 256 * 128;                       // 64*256 bf16

    hipLaunchKernelGGL(prep_kernel, dim3(256), dim3(256), 0, stream,
                       W_dist, W_dir, W_rot, W_pvec, W_relpos, W1, W2, Wcomb, W1T, W2T);
    hipLaunchKernelGGL(node_kernel, dim3(N_NODES / 8), dim3(128), 0, stream,
                       local, pos, W_loc_i, W_loc_j, R_ws, loci_ws, locj_ws);
    hipLaunchKernelGGL(pair_kernel, dim3(N_NODES / NPB), dim3(256), 0, stream,
                       pos, neighbours, resi, chain, batch, mask,
                       ln_scale, ln_bias, b1, b2,
                       R_ws, loci_ws, locj_ws, Wcomb, W1T, W2T, out);
}